// Round 3
// baseline (26.135 us; speedup 1.0000x reference)
//
#include <hip/hip_runtime.h>
#include <math.h>

#define KK 16
#define DD 16
#define NCAT 136
#define NROWS 20480
#define NW 8            // waves per block
#define CPW 17          // categories per wave (8*17 = 136)
#define GS 17           // padded LDS stride for g (odd -> conflict-free)
#define EPSF 1e-6f
#define LOG2PI_F 1.8378770664093453f
#define INV_SQRT2 0.70710678118654752f
#define NBLOCKS (NROWS / 64)   // 320
#define FIXSCALE 4294967296.0  // 2^32

// Branch-free erf, Abramowitz-Stegun 7.1.26 (max abs err ~1.5e-7).
__device__ __forceinline__ float erf_fast(float x) {
    float s  = copysignf(1.0f, x);
    float ax = fabsf(x);
    float t  = __builtin_amdgcn_rcpf(fmaf(0.3275911f, ax, 1.0f));
    float y  = t * fmaf(t, fmaf(t, fmaf(t, fmaf(t, 1.061405429f, -1.453152027f),
                                        1.421413741f), -0.284496736f), 0.254829592f);
    return s * (1.0f - y * __expf(-ax * ax));
}

// ---------------------------------------------------------------------------
// Single kernel. Block = 512 threads = 8 waves, owns 64 rows; wave w handles
// categories [17w,17w+17) for row = lane. Block partial -> fixed-point int64
// atomicAdd (deterministic); last block (atomic counter) writes d_out.
// d_ws[0..7]  : u64 fixed-point sum   (zeroed by hipMemsetAsync each call)
// d_ws[8..11] : u32 completion counter
// ---------------------------------------------------------------------------
__global__ __launch_bounds__(512) void latent_main(
    const float* __restrict__ z,
    const float* __restrict__ pi,
    const float* __restrict__ mu,
    unsigned long long* __restrict__ ws_sum,
    unsigned int* __restrict__ ws_cnt,
    float* __restrict__ out)
{
    __shared__ float  g_s[64 * GS];
    __shared__ float  zz_s[64];
    __shared__ float4 sC4[NCAT];   // (C, recip*sq, sq, sum mu_B^2)
    __shared__ float  sK0[NCAT];   // folded per-category constant
    __shared__ float  comb_m[NW * 64];
    __shared__ float  comb_s[NW * 64];

    const int tid  = threadIdx.x;
    const int w    = tid >> 6;
    const int lane = tid & 63;
    const int row  = blockIdx.x * 64 + lane;

    // --- Phase A: z row -> g columns (wave w does cols 2w, 2w+1), zz (wave 0)
    const float* zr = z + row * DD;
    float zv[DD];
    #pragma unroll
    for (int i = 0; i < 4; ++i) {
        float4 v = reinterpret_cast<const float4*>(zr)[i];
        zv[4 * i + 0] = v.x; zv[4 * i + 1] = v.y;
        zv[4 * i + 2] = v.z; zv[4 * i + 3] = v.w;
    }
    {
        const int k0 = 2 * w, k1 = 2 * w + 1;
        float g0 = 0.f, g1 = 0.f;
        #pragma unroll
        for (int d = 0; d < DD; ++d) {
            g0 = fmaf(zv[d], mu[d * KK + k0], g0);
            g1 = fmaf(zv[d], mu[d * KK + k1], g1);
        }
        g_s[lane * GS + k0] = g0;
        g_s[lane * GS + k1] = g1;
    }
    if (w == 0) {
        float zz = 0.f;
        #pragma unroll
        for (int d = 0; d < DD; ++d) zz = fmaf(zv[d], zv[d], zz);
        zz_s[lane] = zz;
    }

    // --- Phase B: per-category constants, threads 0..135 (waves 0..2).
    // Each participating wave computes the pi-softmax stats itself (no extra
    // barrier needed).
    if (tid < NCAT) {
        float pv[3];
        float lmax = -1e30f;
        #pragma unroll
        for (int j = 0; j < 3; ++j) {
            int cc = lane + j * 64;
            pv[j] = (cc < NCAT) ? pi[cc] : -1e30f;
            lmax = fmaxf(lmax, pv[j]);
        }
        #pragma unroll
        for (int off = 32; off > 0; off >>= 1)
            lmax = fmaxf(lmax, __shfl_xor(lmax, off, 64));
        float lsum = 0.f;
        #pragma unroll
        for (int j = 0; j < 3; ++j) {
            int cc = lane + j * 64;
            if (cc < NCAT) lsum += __expf(pv[j] - lmax);
        }
        #pragma unroll
        for (int off = 32; off > 0; off >>= 1)
            lsum += __shfl_xor(lsum, off, 64);

        const int c = tid;
        int a = 0, rem = c;
        while (rem >= KK - a) { rem -= KK - a; ++a; }
        const int b = a + rem;

        float inv = 0.f, Cc = 0.f, mb2 = 0.f;
        #pragma unroll
        for (int d = 0; d < DD; ++d) {
            float mb = mu[d * KK + b];
            float ma = mu[d * KK + a];
            float al = mb - ma;
            inv = fmaf(al, al, inv);
            Cc  = fmaf(al, mb, Cc);
            mb2 = fmaf(mb, mb, mb2);
        }
        float recip   = (a == b) ? 0.f : 1.f / inv;
        float clipped = fminf(fmaxf(inv, 1e-12f), 1e30f);
        float sq      = sqrtf(clipped);

        float p = __expf(pi[c] - lmax) / lsum;
        p = fminf(fmaxf(p, EPSF), 1.0f);
        float logpi = __logf(p);

        float k0;
        if (a == b) k0 = logpi - 8.f * LOG2PI_F;
        else        k0 = logpi - 8.f * LOG2PI_F + 0.5f * (LOG2PI_F - __logf(clipped));

        sC4[c] = make_float4(Cc, recip * sq, sq, mb2);
        sK0[c] = k0;
    }
    __syncthreads();   // single barrier: g_s, zz_s, sC4, sK0 all ready

    // --- Phase C: wave w, cats [17w, 17w+17), row = lane. Two-pass LSE. ---
    {
        const int c0 = w * CPW;
        int a = 0, rem = c0;
        while (rem >= KK - a) { rem -= KK - a; ++a; }
        int b = a + rem;

        const float zz = zz_s[lane];
        const float* grow = &g_s[lane * GS];
        float val[CPW];
        float m = -1e30f;
        #pragma unroll
        for (int i = 0; i < CPW; ++i) {
            const int c = c0 + i;
            float4 k  = sC4[c];                  // wave-uniform broadcast read
            float k0  = sK0[c];
            float ga  = grow[a];
            float gb  = grow[b];
            float bsq = fmaf(-2.f, gb, zz) + k.w;
            float sab = gb - ga - k.x;
            float e2r = sab * k.y;               // = -nu*sq
            float t   = fmaf(e2r, e2r, -bsq);    // nu^2*inv - bsq
            float e1  = (k.z + e2r) * INV_SQRT2;
            float e2  = e2r * INV_SQRT2;
            float cd  = 0.5f * (erf_fast(e1) - erf_fast(e2));
            cd = fminf(fmaxf(cd, EPSF), 1e30f);
            float vn  = fmaf(0.5f, t, k0) + __logf(cd);
            float vd  = fmaf(-0.5f, bsq, k0);
            val[i] = (a == b) ? vd : vn;         // one cndmask
            m = fmaxf(m, val[i]);
            if (++b == KK) { ++a; b = a; }
        }
        float ssum = 0.f;
        #pragma unroll
        for (int i = 0; i < CPW; ++i) ssum += __expf(val[i] - m);
        comb_m[w * 64 + lane] = m;
        comb_s[w * 64 + lane] = ssum;
    }
    __syncthreads();

    // --- merge 8 wave-partials per row, block-sum, fixed-point atomic ---
    if (w == 0) {
        float M = comb_m[lane], S = comb_s[lane];
        #pragma unroll
        for (int ww = 1; ww < NW; ++ww) {
            float mm = comb_m[ww * 64 + lane];
            float ss = comb_s[ww * 64 + lane];
            float nm = fmaxf(M, mm);
            S = S * __expf(M - nm) + ss * __expf(mm - nm);
            M = nm;
        }
        float lp = M + __logf(S);
        #pragma unroll
        for (int off = 32; off > 0; off >>= 1)
            lp += __shfl_xor(lp, off, 64);

        if (lane == 0) {
            long long fx = (long long)((double)lp * FIXSCALE);
            atomicAdd(ws_sum, (unsigned long long)fx);
            __threadfence();
            unsigned int done = atomicAdd(ws_cnt, 1u);
            if (done == NBLOCKS - 1) {
                __threadfence();
                long long tot = (long long)(*(volatile unsigned long long*)ws_sum);
                out[0] = (float)((double)tot * (1.0 / FIXSCALE) / (double)NROWS);
            }
        }
    }
}

extern "C" void kernel_launch(void* const* d_in, const int* in_sizes, int n_in,
                              void* d_out, int out_size, void* d_ws, size_t ws_size,
                              hipStream_t stream) {
    const float* z  = (const float*)d_in[0];   // (2048,10,16) f32
    const float* pi = (const float*)d_in[1];   // (1,136) f32
    const float* mu = (const float*)d_in[2];   // (16,16) f32
    float* out      = (float*)d_out;           // scalar f32

    unsigned long long* ws_sum = (unsigned long long*)d_ws;
    unsigned int*       ws_cnt = (unsigned int*)((char*)d_ws + 8);

    hipMemsetAsync(d_ws, 0, 16, stream);       // zero sum + counter each call
    latent_main<<<NBLOCKS, 512, 0, stream>>>(z, pi, mu, ws_sum, ws_cnt, out);
}